// Round 7
// baseline (1840.014 us; speedup 1.0000x reference)
//
#include <hip/hip_runtime.h>
#include <hip/hip_bf16.h>
#include <stdint.h>

typedef __bf16 bf16_t;
typedef __bf16 bf16x4 __attribute__((ext_vector_type(4)));
typedef __bf16 bf16x8 __attribute__((ext_vector_type(8)));
typedef float f32x4 __attribute__((ext_vector_type(4)));

#define LDS_CAST(p) ((__attribute__((address_space(3))) void*)(p))
#define GLB_CAST(p) ((const __attribute__((address_space(1))) void*)(p))

__device__ __forceinline__ void gl_lds16(const void* g, void* l) {
  __builtin_amdgcn_global_load_lds(GLB_CAST(g), LDS_CAST(l), 16, 0, 0);
}

#define MFMA16(a,b,c) __builtin_amdgcn_mfma_f32_16x16x32_bf16((a),(b),(c),0,0,0)
#define BARRIER() __builtin_amdgcn_s_barrier()

template<int N> __device__ __forceinline__ void vmw() {
  if constexpr (N == 6)      asm volatile("s_waitcnt vmcnt(6)" ::: "memory");
  else if constexpr (N == 4) asm volatile("s_waitcnt vmcnt(4)" ::: "memory");
  else if constexpr (N == 0) asm volatile("s_waitcnt vmcnt(0)" ::: "memory");
  // N == -1: no wait
}

static constexpr int M_TOT = 4096, H_DIM = 4096, I_DIM = 14336;

// ---------------------------------------------------------------------------
// fp32 -> bf16 conversion (float4 in, bf16x4 out), grid-stride
// ---------------------------------------------------------------------------
__global__ __launch_bounds__(256)
void k_conv(const float4* __restrict__ src, bf16x4* __restrict__ dst, long n4)
{
  long stride = (long)gridDim.x * blockDim.x;
  for (long i = (long)blockIdx.x * blockDim.x + threadIdx.x; i < n4; i += stride) {
    float4 v = src[i];
    bf16x4 o;
    o[0] = (bf16_t)v.x; o[1] = (bf16_t)v.y; o[2] = (bf16_t)v.z; o[3] = (bf16_t)v.w;
    dst[i] = o;
  }
}

// ===========================================================================
// GEMM1: A[M,I] = silu(X Wg^T) * (X Wu^T). BM=128, BN=128, BK=32.
// 256 thr / 4 waves (2M x 2N); per wave 64x64 (G) + 64x64 (U), 32 MFMA/tile.
// 3 LDS bufs x 24 KiB (X 8K | G 8K | U 8K) = 72 KiB -> 2 blocks/CU.
// Lead-2 staging, 6 loads/tile/wave, vmcnt(6) counted wait, 1 barrier/tile.
// Swizzle (proven 0-conflict): stored colb ^= ((row>>3)&1)<<5, src pre-XOR'd.
// ===========================================================================
__global__ __launch_bounds__(256, 2)
void k_gateup4(const bf16_t* __restrict__ X, const bf16_t* __restrict__ Wg,
               const bf16_t* __restrict__ Wu, bf16_t* __restrict__ Aout)
{
  __shared__ __align__(1024) char lds[3 * 24576];
  const int tid = threadIdx.x, wave = tid >> 6, lane = tid & 63;
  const int lr = lane & 15, kg = lane >> 4;
  const int wm = wave >> 1, wn = wave & 1;

  // tn-major XCD mapping: 32 consecutive blocks on an XCD share one tn
  const int bid = blockIdx.x;                  // grid = 3584
  const int bq  = bid >> 3;                    // 0..447
  const int tn  = (bid & 7) * 14 + (bq >> 5);  // 0..111
  const int tm  = bq & 31;                     // 0..31

  // staging: 16 rows x 64B per instruction; wave w covers rows w*32..w*32+31
  const int sr16  = lane >> 2;                                  // 0..15
  const int scolb = ((lane & 3) * 16) ^ (((lane >> 5) & 1) << 5);

  const bf16_t* gXw = X  + (size_t)(tm * 128 + wave * 32 + sr16) * H_DIM + (scolb >> 1);
  const bf16_t* gGw = Wg + (size_t)(tn * 128 + wave * 32 + sr16) * H_DIM + (scolb >> 1);
  const bf16_t* gUw = Wu + (size_t)(tn * 128 + wave * 32 + sr16) * H_DIM + (scolb >> 1);
  const size_t rstep = (size_t)16 * H_DIM;     // +16 rows

  const int ck   = (kg * 16) ^ (((lr >> 3) & 1) << 5);
  const int offA = (wm * 64 + lr) * 64 + ck;           // + m*1024, m=0..3
  const int offG = 8192  + (wn * 64 + lr) * 64 + ck;   // + n*1024, n=0..3
  const int offU = 16384 + (wn * 64 + lr) * 64 + ck;

  const f32x4 vz = {0.f, 0.f, 0.f, 0.f};
  f32x4 accg[4][4], accu[4][4];
#pragma unroll
  for (int m = 0; m < 4; ++m)
#pragma unroll
    for (int n = 0; n < 4; ++n) { accg[m][n] = vz; accu[m][n] = vz; }

#define G1_STAGE(dst, kc)                                                    \
  { char* d_ = (dst) + wave * 2048;                                          \
    gl_lds16(gXw + (kc),         d_);                                        \
    gl_lds16(gXw + rstep + (kc), d_ + 1024);                                 \
    gl_lds16(gGw + (kc),         d_ + 8192);                                 \
    gl_lds16(gGw + rstep + (kc), d_ + 9216);                                 \
    gl_lds16(gUw + (kc),         d_ + 16384);                                \
    gl_lds16(gUw + rstep + (kc), d_ + 17408); }

#define G1_TILE(bb, WAITN, DO_BAR)                                           \
  { bf16x8 a[4], bg[4], bu[4];                                               \
    _Pragma("unroll") for (int f = 0; f < 4; ++f) {                          \
      a[f]  = *(const bf16x8*)((bb) + offA + f * 1024);                      \
      bg[f] = *(const bf16x8*)((bb) + offG + f * 1024);                      \
      bu[f] = *(const bf16x8*)((bb) + offU + f * 1024); }                    \
    __builtin_amdgcn_s_setprio(1);                                           \
    _Pragma("unroll") for (int m = 0; m < 4; ++m)                            \
    _Pragma("unroll") for (int n = 0; n < 4; ++n) {                          \
      accg[m][n] = MFMA16(a[m], bg[n], accg[m][n]);                          \
      accu[m][n] = MFMA16(a[m], bu[n], accu[m][n]); }                        \
    __builtin_amdgcn_s_setprio(0);                                           \
    vmw<WAITN>();                                                            \
    if (DO_BAR) BARRIER(); }

  char* B0 = lds; char* B1 = lds + 24576; char* B2 = lds + 49152;
  // prologue: stage tiles 0,1
  G1_STAGE(B0, 0);
  G1_STAGE(B1, 32);
  vmw<6>(); BARRIER();

  // rotation: tile T reads p_cur, stages T+2 into p_prev (buffer T-1 read)
  char *p_prev = B2, *p_cur = B0, *p_next = B1;
  const int NT = H_DIM / 32;                   // 128
  for (int T = 0; T <= NT - 3; ++T) {
    G1_STAGE(p_prev, (T + 2) * 32);
    G1_TILE(p_cur, 6, true);
    char* t_ = p_prev; p_prev = p_cur; p_cur = p_next; p_next = t_;
  }
  G1_TILE(p_cur, 0, true);
  { char* t_ = p_cur; p_cur = p_next; p_next = t_; }
  G1_TILE(p_cur, -1, false);
#undef G1_TILE
#undef G1_STAGE

  // epilogue: C/D col = lane&15, row = (lane>>4)*4 + e
  const int r0 = tm * 128 + wm * 64 + kg * 4;
  const int c0 = tn * 128 + wn * 64 + lr;
#pragma unroll
  for (int m = 0; m < 4; ++m)
#pragma unroll
    for (int n = 0; n < 4; ++n)
#pragma unroll
      for (int e = 0; e < 4; ++e) {
        float g = accg[m][n][e];
        float u = accu[m][n][e];
        float s = g / (1.0f + __expf(-g));
        Aout[(size_t)(r0 + m * 16 + e) * I_DIM + c0 + n * 16] = (bf16_t)(s * u);
      }
}

// ===========================================================================
// GEMM2: D[M,H] = A Wd^T. BM=BN=128, BK=32, K=I_DIM.
// 256 thr / 4 waves (2x2); per wave 64x64, 16 MFMA/tile.
// 3 LDS bufs x 16 KiB (A 8K | B 8K) = 48 KiB -> 3 blocks/CU.
// Lead-2, 4 loads/tile/wave, vmcnt(4), 1 barrier/tile.
// ===========================================================================
__global__ __launch_bounds__(256, 3)
void k_down4(const bf16_t* __restrict__ Aa, const bf16_t* __restrict__ Wd,
             float* __restrict__ D)
{
  __shared__ __align__(1024) char lds[3 * 16384];
  const int tid = threadIdx.x, wave = tid >> 6, lane = tid & 63;
  const int lr = lane & 15, kg = lane >> 4;
  const int wm = wave >> 1, wn = wave & 1;

  const int bid = blockIdx.x;                  // grid = 1024
  const int bq  = bid >> 3;                    // 0..127
  const int tn  = (bid & 7) * 4 + (bq >> 5);   // 0..31
  const int tm  = bq & 31;                     // 0..31

  const int sr16  = lane >> 2;
  const int scolb = ((lane & 3) * 16) ^ (((lane >> 5) & 1) << 5);

  const bf16_t* gAw = Aa + (size_t)(tm * 128 + wave * 32 + sr16) * I_DIM + (scolb >> 1);
  const bf16_t* gBw = Wd + (size_t)(tn * 128 + wave * 32 + sr16) * I_DIM + (scolb >> 1);
  const size_t rstep = (size_t)16 * I_DIM;

  const int ck   = (kg * 16) ^ (((lr >> 3) & 1) << 5);
  const int offA = (wm * 64 + lr) * 64 + ck;           // + m*1024
  const int offB = 8192 + (wn * 64 + lr) * 64 + ck;    // + n*1024

  const f32x4 vz = {0.f, 0.f, 0.f, 0.f};
  f32x4 acc[4][4];
#pragma unroll
  for (int m = 0; m < 4; ++m)
#pragma unroll
    for (int n = 0; n < 4; ++n) acc[m][n] = vz;

#define G2_STAGE(dst, kc)                                                    \
  { char* d_ = (dst) + wave * 2048;                                          \
    gl_lds16(gAw + (kc),         d_);                                        \
    gl_lds16(gAw + rstep + (kc), d_ + 1024);                                 \
    gl_lds16(gBw + (kc),         d_ + 8192);                                 \
    gl_lds16(gBw + rstep + (kc), d_ + 9216); }

#define G2_TILE(bb, WAITN, DO_BAR)                                           \
  { bf16x8 a[4], b[4];                                                       \
    _Pragma("unroll") for (int f = 0; f < 4; ++f) {                          \
      a[f] = *(const bf16x8*)((bb) + offA + f * 1024);                       \
      b[f] = *(const bf16x8*)((bb) + offB + f * 1024); }                     \
    __builtin_amdgcn_s_setprio(1);                                           \
    _Pragma("unroll") for (int m = 0; m < 4; ++m)                            \
    _Pragma("unroll") for (int n = 0; n < 4; ++n)                            \
      acc[m][n] = MFMA16(a[m], b[n], acc[m][n]);                             \
    __builtin_amdgcn_s_setprio(0);                                           \
    vmw<WAITN>();                                                            \
    if (DO_BAR) BARRIER(); }

  char* B0 = lds; char* B1 = lds + 16384; char* B2 = lds + 32768;
  G2_STAGE(B0, 0);
  G2_STAGE(B1, 32);
  vmw<4>(); BARRIER();

  char *p_prev = B2, *p_cur = B0, *p_next = B1;
  const int NT = I_DIM / 32;                   // 448
  for (int T = 0; T <= NT - 3; ++T) {
    G2_STAGE(p_prev, (T + 2) * 32);
    G2_TILE(p_cur, 4, true);
    char* t_ = p_prev; p_prev = p_cur; p_cur = p_next; p_next = t_;
  }
  G2_TILE(p_cur, 0, true);
  { char* t_ = p_cur; p_cur = p_next; p_next = t_; }
  G2_TILE(p_cur, -1, false);
#undef G2_TILE
#undef G2_STAGE

  const int r0 = tm * 128 + wm * 64 + kg * 4;
  const int c0 = tn * 128 + wn * 64 + lr;
#pragma unroll
  for (int m = 0; m < 4; ++m)
#pragma unroll
    for (int n = 0; n < 4; ++n)
#pragma unroll
      for (int e = 0; e < 4; ++e)
        D[(size_t)(r0 + m * 16 + e) * H_DIM + c0 + n * 16] = acc[m][n][e];
}

// ---------------------------------------------------------------------------
extern "C" void kernel_launch(void* const* d_in, const int* in_sizes, int n_in,
                              void* d_out, int out_size, void* d_ws, size_t ws_size,
                              hipStream_t stream) {
  const float* x  = (const float*)d_in[0];
  const float* wg = (const float*)d_in[1];
  const float* wu = (const float*)d_in[2];
  const float* wd = (const float*)d_in[3];
  float* out = (float*)d_out;

  const size_t A_BYTES = (size_t)M_TOT * I_DIM * 2;
  const size_t X_BYTES = (size_t)M_TOT * H_DIM * 2;
  const size_t W_BYTES = (size_t)I_DIM * H_DIM * 2;
  char* ws = (char*)d_ws;
  bf16_t* Ab  = (bf16_t*)(ws);
  bf16_t* Xb  = (bf16_t*)(ws + A_BYTES);
  bf16_t* Wgb = (bf16_t*)(ws + A_BYTES + X_BYTES);
  bf16_t* Wub = (bf16_t*)(ws + A_BYTES + X_BYTES + W_BYTES);
  bf16_t* Wdb = Wgb;   // reuse after k_gateup4 consumed Wgb

  const long nX = (long)M_TOT * H_DIM / 4;
  const long nW = (long)I_DIM * H_DIM / 4;

  k_conv<<<dim3(2048), dim3(256), 0, stream>>>((const float4*)x,  (bf16x4*)Xb,  nX);
  k_conv<<<dim3(2048), dim3(256), 0, stream>>>((const float4*)wg, (bf16x4*)Wgb, nW);
  k_conv<<<dim3(2048), dim3(256), 0, stream>>>((const float4*)wu, (bf16x4*)Wub, nW);

  k_gateup4<<<dim3(32 * 112), dim3(256), 0, stream>>>(Xb, Wgb, Wub, Ab);

  k_conv<<<dim3(2048), dim3(256), 0, stream>>>((const float4*)wd, (bf16x4*)Wdb, nW);

  k_down4<<<dim3(32 * 32), dim3(256), 0, stream>>>(Ab, Wdb, out);
}

// Round 8
// 1450.088 us; speedup vs baseline: 1.2689x; 1.2689x over previous
//
#include <hip/hip_runtime.h>
#include <hip/hip_bf16.h>
#include <stdint.h>

typedef __bf16 bf16_t;
typedef __bf16 bf16x4 __attribute__((ext_vector_type(4)));
typedef __bf16 bf16x8 __attribute__((ext_vector_type(8)));
typedef float f32x4 __attribute__((ext_vector_type(4)));

#define LDS_CAST(p) ((__attribute__((address_space(3))) void*)(p))
#define GLB_CAST(p) ((const __attribute__((address_space(1))) void*)(p))

__device__ __forceinline__ void gl_lds16(const void* g, void* l) {
  __builtin_amdgcn_global_load_lds(GLB_CAST(g), LDS_CAST(l), 16, 0, 0);
}

#define MFMA16(a,b,c) __builtin_amdgcn_mfma_f32_16x16x32_bf16((a),(b),(c),0,0,0)
#define BARRIER() __builtin_amdgcn_s_barrier()
#define LGKM0()  asm volatile("s_waitcnt lgkmcnt(0)" ::: "memory")
#define PRIO(n)  __builtin_amdgcn_s_setprio(n)

template<int N> __device__ __forceinline__ void vmw() {
  if constexpr (N == 4)      asm volatile("s_waitcnt vmcnt(4)" ::: "memory");
  else if constexpr (N == 2) asm volatile("s_waitcnt vmcnt(2)" ::: "memory");
  else if constexpr (N == 0) asm volatile("s_waitcnt vmcnt(0)" ::: "memory");
  // N == -1: no wait
}

static constexpr int M_TOT = 4096, H_DIM = 4096, I_DIM = 14336;

// ---------------------------------------------------------------------------
// fp32 -> bf16 conversion (float4 in, bf16x4 out), grid-stride
// ---------------------------------------------------------------------------
__global__ __launch_bounds__(256)
void k_conv(const float4* __restrict__ src, bf16x4* __restrict__ dst, long n4)
{
  long stride = (long)gridDim.x * blockDim.x;
  for (long i = (long)blockIdx.x * blockDim.x + threadIdx.x; i < n4; i += stride) {
    float4 v = src[i];
    bf16x4 o;
    o[0] = (bf16_t)v.x; o[1] = (bf16_t)v.y; o[2] = (bf16_t)v.z; o[3] = (bf16_t)v.w;
    dst[i] = o;
  }
}

// ===========================================================================
// GEMM1: A[M,I] = silu(X Wg^T) * (X Wu^T). BM=256, BN=128, BK=64.
// 512 thr / 8 waves (2M x 4N), per-wave 128 x (32 G + 32 U).
// 2 LDS buffers x 64 KiB; each BK=64 tile = two BK=32 subtiles in the proven
// round-5 layout (64B rows, XOR-bit5^rowbit3 swizzle, 0 conflicts).
// Buffer map: Xkf0 @0 (16K) | Xkf1 @16K | Gkf0 @32K (8K) | Gkf1 @40K |
//             Ukf0 @48K | Ukf1 @56K.
// 4 phases per K-tile (m201 port): {ds_read subtile || stage chunk ->
//  s_barrier -> lgkmcnt(0) -> setprio(1)+16 MFMA+setprio(0) -> vmcnt(4) ->
//  s_barrier}. Chunk c_p staged at phase p, read 4 phases later.
// ===========================================================================
__global__ __launch_bounds__(512, 2)
void k_gateup8(const bf16_t* __restrict__ X, const bf16_t* __restrict__ Wg,
               const bf16_t* __restrict__ Wu, bf16_t* __restrict__ Aout)
{
  __shared__ __align__(1024) char lds[131072];
  const int tid = threadIdx.x, wave = tid >> 6, lane = tid & 63;
  const int lr = lane & 15, kg = lane >> 4;
  const int xm = ((lr >> 3) & 1) << 5;
  const int wm = wave >> 2, wn = wave & 3;
  const int wb = wave * 1024;

  // tn-major XCD mapping (proven: halves FETCH)
  const int bid = blockIdx.x;                 // grid = 1792
  const int bq  = bid >> 3;                   // 0..223
  const int tn  = (bid & 7) * 14 + (bq >> 4); // 0..111
  const int tm  = bq & 15;                    // 0..15

  const int srow  = tid >> 2;                                   // 0..127
  const int scolb = ((tid & 3) * 16) ^ (((tid >> 5) & 1) << 5); // pre-swizzled

  const bf16_t* gX = X  + (size_t)(tm * 256 + srow) * H_DIM + (scolb >> 1);
  const bf16_t* gG = Wg + (size_t)(tn * 128 + srow) * H_DIM + (scolb >> 1);
  const bf16_t* gU = Wu + (size_t)(tn * 128 + srow) * H_DIM + (scolb >> 1);
  const size_t xh = (size_t)128 * H_DIM;

  const int ck   = (kg * 16) ^ xm;
  const int offA = (wm * 128 + lr) * 64 + ck;   // + f*1024 within Xkf subtile
  const int offG = (wn * 32 + lr) * 64 + ck;    // + n*1024 within G/Ukf subtile

  const f32x4 vz = {0.f, 0.f, 0.f, 0.f};
  f32x4 accg[8][2], accu[8][2];
#pragma unroll
  for (int m = 0; m < 8; ++m)
#pragma unroll
    for (int n = 0; n < 2; ++n) { accg[m][n] = vz; accu[m][n] = vz; }

  // prologue: stage tile0 chunks c1..c4 (issue order = chunk order)
  gl_lds16(gX,           lds + 0     + wb);
  gl_lds16(gX + xh,      lds + 8192  + wb);   // c1 = Xkf0
  gl_lds16(gG,           lds + 32768 + wb);
  gl_lds16(gU,           lds + 49152 + wb);   // c2 = Gkf0+Ukf0
  gl_lds16(gX + 32,      lds + 16384 + wb);
  gl_lds16(gX + xh + 32, lds + 24576 + wb);   // c3 = Xkf1
  gl_lds16(gG + 32,      lds + 40960 + wb);
  gl_lds16(gU + 32,      lds + 57344 + wb);   // c4 = Gkf1+Ukf1
  vmw<4>(); BARRIER();

  const int NT = H_DIM / 64;                  // 64
  for (int T = 0; T <= NT - 2; ++T) {
    const char* bb = lds + (T & 1) * 65536;
    char* sb = lds + ((T + 1) & 1) * 65536 + wb;
    const bf16_t* gXn = gX + (T + 1) * 64;
    const bf16_t* gGn = gG + (T + 1) * 64;
    const bf16_t* gUn = gU + (T + 1) * 64;
    bf16x8 bg0, bg1, bu0, bu1;
    { // P1: kf0, m 0..3   (reads c1,c2; stages c1')
      bf16x8 a[4];
#pragma unroll
      for (int f = 0; f < 4; ++f) a[f] = *(const bf16x8*)(bb + offA + f * 1024);
      bg0 = *(const bf16x8*)(bb + 32768 + offG);
      bg1 = *(const bf16x8*)(bb + 32768 + offG + 1024);
      bu0 = *(const bf16x8*)(bb + 49152 + offG);
      bu1 = *(const bf16x8*)(bb + 49152 + offG + 1024);
      gl_lds16(gXn, sb); gl_lds16(gXn + xh, sb + 8192);
      BARRIER(); LGKM0();
      PRIO(1);
#pragma unroll
      for (int m = 0; m < 4; ++m) {
        accg[m][0] = MFMA16(a[m], bg0, accg[m][0]);
        accg[m][1] = MFMA16(a[m], bg1, accg[m][1]);
        accu[m][0] = MFMA16(a[m], bu0, accu[m][0]);
        accu[m][1] = MFMA16(a[m], bu1, accu[m][1]);
      }
      PRIO(0);
      vmw<4>(); BARRIER();
    }
    { // P2: kf0, m 4..7   (reads c1; stages c2')
      bf16x8 a[4];
#pragma unroll
      for (int f = 0; f < 4; ++f) a[f] = *(const bf16x8*)(bb + offA + (f + 4) * 1024);
      gl_lds16(gGn, sb + 32768); gl_lds16(gUn, sb + 49152);
      BARRIER(); LGKM0();
      PRIO(1);
#pragma unroll
      for (int m = 0; m < 4; ++m) {
        accg[4 + m][0] = MFMA16(a[m], bg0, accg[4 + m][0]);
        accg[4 + m][1] = MFMA16(a[m], bg1, accg[4 + m][1]);
        accu[4 + m][0] = MFMA16(a[m], bu0, accu[4 + m][0]);
        accu[4 + m][1] = MFMA16(a[m], bu1, accu[4 + m][1]);
      }
      PRIO(0);
      vmw<4>(); BARRIER();
    }
    { // P3: kf1, m 0..3   (reads c3,c4; stages c3')
      bf16x8 a[4];
#pragma unroll
      for (int f = 0; f < 4; ++f) a[f] = *(const bf16x8*)(bb + 16384 + offA + f * 1024);
      bg0 = *(const bf16x8*)(bb + 40960 + offG);
      bg1 = *(const bf16x8*)(bb + 40960 + offG + 1024);
      bu0 = *(const bf16x8*)(bb + 57344 + offG);
      bu1 = *(const bf16x8*)(bb + 57344 + offG + 1024);
      gl_lds16(gXn + 32, sb + 16384); gl_lds16(gXn + xh + 32, sb + 24576);
      BARRIER(); LGKM0();
      PRIO(1);
#pragma unroll
      for (int m = 0; m < 4; ++m) {
        accg[m][0] = MFMA16(a[m], bg0, accg[m][0]);
        accg[m][1] = MFMA16(a[m], bg1, accg[m][1]);
        accu[m][0] = MFMA16(a[m], bu0, accu[m][0]);
        accu[m][1] = MFMA16(a[m], bu1, accu[m][1]);
      }
      PRIO(0);
      vmw<4>(); BARRIER();
    }
    { // P4: kf1, m 4..7   (reads c3; stages c4')
      bf16x8 a[4];
#pragma unroll
      for (int f = 0; f < 4; ++f) a[f] = *(const bf16x8*)(bb + 16384 + offA + (f + 4) * 1024);
      gl_lds16(gGn + 32, sb + 40960); gl_lds16(gUn + 32, sb + 57344);
      BARRIER(); LGKM0();
      PRIO(1);
#pragma unroll
      for (int m = 0; m < 4; ++m) {
        accg[4 + m][0] = MFMA16(a[m], bg0, accg[4 + m][0]);
        accg[4 + m][1] = MFMA16(a[m], bg1, accg[4 + m][1]);
        accu[4 + m][0] = MFMA16(a[m], bu0, accu[4 + m][0]);
        accu[4 + m][1] = MFMA16(a[m], bu1, accu[4 + m][1]);
      }
      PRIO(0);
      vmw<4>(); BARRIER();
    }
  }
  { // last tile: no staging; drain 2 -> 0
    const char* bb = lds + ((NT - 1) & 1) * 65536;
    bf16x8 bg0, bg1, bu0, bu1;
    { bf16x8 a[4];
#pragma unroll
      for (int f = 0; f < 4; ++f) a[f] = *(const bf16x8*)(bb + offA + f * 1024);
      bg0 = *(const bf16x8*)(bb + 32768 + offG);
      bg1 = *(const bf16x8*)(bb + 32768 + offG + 1024);
      bu0 = *(const bf16x8*)(bb + 49152 + offG);
      bu1 = *(const bf16x8*)(bb + 49152 + offG + 1024);
      BARRIER(); LGKM0(); PRIO(1);
#pragma unroll
      for (int m = 0; m < 4; ++m) {
        accg[m][0] = MFMA16(a[m], bg0, accg[m][0]);
        accg[m][1] = MFMA16(a[m], bg1, accg[m][1]);
        accu[m][0] = MFMA16(a[m], bu0, accu[m][0]);
        accu[m][1] = MFMA16(a[m], bu1, accu[m][1]); }
      PRIO(0); vmw<2>(); BARRIER(); }
    { bf16x8 a[4];
#pragma unroll
      for (int f = 0; f < 4; ++f) a[f] = *(const bf16x8*)(bb + offA + (f + 4) * 1024);
      BARRIER(); LGKM0(); PRIO(1);
#pragma unroll
      for (int m = 0; m < 4; ++m) {
        accg[4 + m][0] = MFMA16(a[m], bg0, accg[4 + m][0]);
        accg[4 + m][1] = MFMA16(a[m], bg1, accg[4 + m][1]);
        accu[4 + m][0] = MFMA16(a[m], bu0, accu[4 + m][0]);
        accu[4 + m][1] = MFMA16(a[m], bu1, accu[4 + m][1]); }
      PRIO(0); vmw<0>(); BARRIER(); }
    { bf16x8 a[4];
#pragma unroll
      for (int f = 0; f < 4; ++f) a[f] = *(const bf16x8*)(bb + 16384 + offA + f * 1024);
      bg0 = *(const bf16x8*)(bb + 40960 + offG);
      bg1 = *(const bf16x8*)(bb + 40960 + offG + 1024);
      bu0 = *(const bf16x8*)(bb + 57344 + offG);
      bu1 = *(const bf16x8*)(bb + 57344 + offG + 1024);
      LGKM0(); PRIO(1);
#pragma unroll
      for (int m = 0; m < 4; ++m) {
        accg[m][0] = MFMA16(a[m], bg0, accg[m][0]);
        accg[m][1] = MFMA16(a[m], bg1, accg[m][1]);
        accu[m][0] = MFMA16(a[m], bu0, accu[m][0]);
        accu[m][1] = MFMA16(a[m], bu1, accu[m][1]); }
      PRIO(0); }
    { bf16x8 a[4];
#pragma unroll
      for (int f = 0; f < 4; ++f) a[f] = *(const bf16x8*)(bb + 16384 + offA + (f + 4) * 1024);
      LGKM0(); PRIO(1);
#pragma unroll
      for (int m = 0; m < 4; ++m) {
        accg[4 + m][0] = MFMA16(a[m], bg0, accg[4 + m][0]);
        accg[4 + m][1] = MFMA16(a[m], bg1, accg[4 + m][1]);
        accu[4 + m][0] = MFMA16(a[m], bu0, accu[4 + m][0]);
        accu[4 + m][1] = MFMA16(a[m], bu1, accu[4 + m][1]); }
      PRIO(0); }
  }

  // epilogue: C/D col = lane&15, row = (lane>>4)*4 + e
  const int r0 = tm * 256 + wm * 128 + kg * 4;
  const int c0 = tn * 128 + wn * 32 + lr;
#pragma unroll
  for (int m = 0; m < 8; ++m)
#pragma unroll
    for (int n = 0; n < 2; ++n)
#pragma unroll
      for (int e = 0; e < 4; ++e) {
        float g = accg[m][n][e];
        float u = accu[m][n][e];
        float s = g / (1.0f + __expf(-g));
        Aout[(size_t)(r0 + m * 16 + e) * I_DIM + c0 + n * 16] = (bf16_t)(s * u);
      }
}

// ===========================================================================
// GEMM2: D[M,H] = A Wd^T. BM=BN=256, BK=64, K=I_DIM. Per-wave 128x64.
// Same 4-phase pipeline. Buffer map: Akf0 @0 (16K) | Akf1 @16K |
// Bkf0 @32K (16K) | Bkf1 @48K.  Chunks: c1=Akf0, c2=Bkf0, c3=Akf1, c4=Bkf1.
// ===========================================================================
__global__ __launch_bounds__(512, 2)
void k_down8(const bf16_t* __restrict__ Aa, const bf16_t* __restrict__ Wd,
             float* __restrict__ D)
{
  __shared__ __align__(1024) char lds[131072];
  const int tid = threadIdx.x, wave = tid >> 6, lane = tid & 63;
  const int lr = lane & 15, kg = lane >> 4;
  const int xm = ((lr >> 3) & 1) << 5;
  const int wm = wave >> 2, wn = wave & 3;
  const int wb = wave * 1024;

  const int bid = blockIdx.x;                 // grid = 256
  const int bq  = bid >> 3;                   // 0..31
  const int tn  = (bid & 7) * 2 + (bq >> 4);  // 0..15
  const int tm  = bq & 15;                    // 0..15

  const int srow  = tid >> 2;
  const int scolb = ((tid & 3) * 16) ^ (((tid >> 5) & 1) << 5);

  const bf16_t* gA = Aa + (size_t)(tm * 256 + srow) * I_DIM + (scolb >> 1);
  const bf16_t* gB = Wd + (size_t)(tn * 256 + srow) * I_DIM + (scolb >> 1);
  const size_t hI = (size_t)128 * I_DIM;

  const int ck   = (kg * 16) ^ xm;
  const int offA = (wm * 128 + lr) * 64 + ck;   // + f*1024
  const int offB = (wn * 64 + lr) * 64 + ck;    // + n*1024

  const f32x4 vz = {0.f, 0.f, 0.f, 0.f};
  f32x4 acc[8][4];
#pragma unroll
  for (int m = 0; m < 8; ++m)
#pragma unroll
    for (int n = 0; n < 4; ++n) acc[m][n] = vz;

  gl_lds16(gA,           lds + 0     + wb);
  gl_lds16(gA + hI,      lds + 8192  + wb);   // c1 = Akf0
  gl_lds16(gB,           lds + 32768 + wb);
  gl_lds16(gB + hI,      lds + 40960 + wb);   // c2 = Bkf0
  gl_lds16(gA + 32,      lds + 16384 + wb);
  gl_lds16(gA + hI + 32, lds + 24576 + wb);   // c3 = Akf1
  gl_lds16(gB + 32,      lds + 49152 + wb);
  gl_lds16(gB + hI + 32, lds + 57344 + wb);   // c4 = Bkf1
  vmw<4>(); BARRIER();

  const int NT = I_DIM / 64;                  // 224
  for (int T = 0; T <= NT - 2; ++T) {
    const char* bb = lds + (T & 1) * 65536;
    char* sb = lds + ((T + 1) & 1) * 65536 + wb;
    const bf16_t* gAn = gA + (T + 1) * 64;
    const bf16_t* gBn = gB + (T + 1) * 64;
    bf16x8 bv[4];
    { // P1: kf0, m 0..3 (reads c1,c2; stages c1')
      bf16x8 a[4];
#pragma unroll
      for (int f = 0; f < 4; ++f) a[f] = *(const bf16x8*)(bb + offA + f * 1024);
#pragma unroll
      for (int n = 0; n < 4; ++n) bv[n] = *(const bf16x8*)(bb + 32768 + offB + n * 1024);
      gl_lds16(gAn, sb); gl_lds16(gAn + hI, sb + 8192);
      BARRIER(); LGKM0();
      PRIO(1);
#pragma unroll
      for (int m = 0; m < 4; ++m)
#pragma unroll
        for (int n = 0; n < 4; ++n) acc[m][n] = MFMA16(a[m], bv[n], acc[m][n]);
      PRIO(0);
      vmw<4>(); BARRIER();
    }
    { // P2: kf0, m 4..7 (stages c2')
      bf16x8 a[4];
#pragma unroll
      for (int f = 0; f < 4; ++f) a[f] = *(const bf16x8*)(bb + offA + (f + 4) * 1024);
      gl_lds16(gBn, sb + 32768); gl_lds16(gBn + hI, sb + 40960);
      BARRIER(); LGKM0();
      PRIO(1);
#pragma unroll
      for (int m = 0; m < 4; ++m)
#pragma unroll
        for (int n = 0; n < 4; ++n) acc[4 + m][n] = MFMA16(a[m], bv[n], acc[4 + m][n]);
      PRIO(0);
      vmw<4>(); BARRIER();
    }
    { // P3: kf1, m 0..3 (reads c3,c4; stages c3')
      bf16x8 a[4];
#pragma unroll
      for (int f = 0; f < 4; ++f) a[f] = *(const bf16x8*)(bb + 16384 + offA + f * 1024);
#pragma unroll
      for (int n = 0; n < 4; ++n) bv[n] = *(const bf16x8*)(bb + 49152 + offB + n * 1024);
      gl_lds16(gAn + 32, sb + 16384); gl_lds16(gAn + hI + 32, sb + 24576);
      BARRIER(); LGKM0();
      PRIO(1);
#pragma unroll
      for (int m = 0; m < 4; ++m)
#pragma unroll
        for (int n = 0; n < 4; ++n) acc[m][n] = MFMA16(a[m], bv[n], acc[m][n]);
      PRIO(0);
      vmw<4>(); BARRIER();
    }
    { // P4: kf1, m 4..7 (stages c4')
      bf16x8 a[4];
#pragma unroll
      for (int f = 0; f < 4; ++f) a[f] = *(const bf16x8*)(bb + 16384 + offA + (f + 4) * 1024);
      gl_lds16(gBn + 32, sb + 49152); gl_lds16(gBn + hI + 32, sb + 57344);
      BARRIER(); LGKM0();
      PRIO(1);
#pragma unroll
      for (int m = 0; m < 4; ++m)
#pragma unroll
        for (int n = 0; n < 4; ++n) acc[4 + m][n] = MFMA16(a[m], bv[n], acc[4 + m][n]);
      PRIO(0);
      vmw<4>(); BARRIER();
    }
  }
  { // last tile: drain
    const char* bb = lds + ((NT - 1) & 1) * 65536;
    bf16x8 bv[4];
    { bf16x8 a[4];
#pragma unroll
      for (int f = 0; f < 4; ++f) a[f] = *(const bf16x8*)(bb + offA + f * 1024);
#pragma unroll
      for (int n = 0; n < 4; ++n) bv[n] = *(const bf16x8*)(bb + 32768 + offB + n * 1024);
      BARRIER(); LGKM0(); PRIO(1);
#pragma unroll
      for (int m = 0; m < 4; ++m)
#pragma unroll
        for (int n = 0; n < 4; ++n) acc[m][n] = MFMA16(a[m], bv[n], acc[m][n]);
      PRIO(0); vmw<2>(); BARRIER(); }
    { bf16x8 a[4];
#pragma unroll
      for (int f = 0; f < 4; ++f) a[f] = *(const bf16x8*)(bb + offA + (f + 4) * 1024);
      BARRIER(); LGKM0(); PRIO(1);
#pragma unroll
      for (int m = 0; m < 4; ++m)
#pragma unroll
        for (int n = 0; n < 4; ++n) acc[4 + m][n] = MFMA16(a[m], bv[n], acc[4 + m][n]);
      PRIO(0); vmw<0>(); BARRIER(); }
    { bf16x8 a[4];
#pragma unroll
      for (int f = 0; f < 4; ++f) a[f] = *(const bf16x8*)(bb + 16384 + offA + f * 1024);
#pragma unroll
      for (int n = 0; n < 4; ++n) bv[n] = *(const bf16x8*)(bb + 49152 + offB + n * 1024);
      LGKM0(); PRIO(1);
#pragma unroll
      for (int m = 0; m < 4; ++m)
#pragma unroll
        for (int n = 0; n < 4; ++n) acc[m][n] = MFMA16(a[m], bv[n], acc[m][n]);
      PRIO(0); }
    { bf16x8 a[4];
#pragma unroll
      for (int f = 0; f < 4; ++f) a[f] = *(const bf16x8*)(bb + 16384 + offA + (f + 4) * 1024);
      LGKM0(); PRIO(1);
#pragma unroll
      for (int m = 0; m < 4; ++m)
#pragma unroll
        for (int n = 0; n < 4; ++n) acc[4 + m][n] = MFMA16(a[m], bv[n], acc[4 + m][n]);
      PRIO(0); }
  }

  const int r0 = tm * 256 + wm * 128 + kg * 4;
  const int c0 = tn * 256 + wn * 64 + lr;
#pragma unroll
  for (int m = 0; m < 8; ++m)
#pragma unroll
    for (int n = 0; n < 4; ++n)
#pragma unroll
      for (int e = 0; e < 4; ++e)
        D[(size_t)(r0 + m * 16 + e) * H_DIM + c0 + n * 16] = acc[m][n][e];
}

// ---------------------------------------------------------------------------
extern "C" void kernel_launch(void* const* d_in, const int* in_sizes, int n_in,
                              void* d_out, int out_size, void* d_ws, size_t ws_size,
                              hipStream_t stream) {
  const float* x  = (const float*)d_in[0];
  const float* wg = (const float*)d_in[1];
  const float* wu = (const float*)d_in[2];
  const float* wd = (const float*)d_in[3];
  float* out = (float*)d_out;

  const size_t A_BYTES = (size_t)M_TOT * I_DIM * 2;
  const size_t X_BYTES = (size_t)M_TOT * H_DIM * 2;
  const size_t W_BYTES = (size_t)I_DIM * H_DIM * 2;
  char* ws = (char*)d_ws;
  bf16_t* Ab  = (bf16_t*)(ws);
  bf16_t* Xb  = (bf16_t*)(ws + A_BYTES);
  bf16_t* Wgb = (bf16_t*)(ws + A_BYTES + X_BYTES);
  bf16_t* Wub = (bf16_t*)(ws + A_BYTES + X_BYTES + W_BYTES);
  bf16_t* Wdb = Wgb;   // reuse after k_gateup8 consumed Wgb

  const long nX = (long)M_TOT * H_DIM / 4;
  const long nW = (long)I_DIM * H_DIM / 4;

  k_conv<<<dim3(2048), dim3(256), 0, stream>>>((const float4*)x,  (bf16x4*)Xb,  nX);
  k_conv<<<dim3(2048), dim3(256), 0, stream>>>((const float4*)wg, (bf16x4*)Wgb, nW);
  k_conv<<<dim3(2048), dim3(256), 0, stream>>>((const float4*)wu, (bf16x4*)Wub, nW);

  k_gateup8<<<dim3(16 * 112), dim3(512), 0, stream>>>(Xb, Wgb, Wub, Ab);

  k_conv<<<dim3(2048), dim3(256), 0, stream>>>((const float4*)wd, (bf16x4*)Wdb, nW);

  k_down8<<<dim3(16 * 16), dim3(512), 0, stream>>>(Ab, Wdb, out);
}

// Round 9
// 1418.192 us; speedup vs baseline: 1.2974x; 1.0225x over previous
//
#include <hip/hip_runtime.h>
#include <hip/hip_bf16.h>
#include <stdint.h>

typedef __bf16 bf16_t;
typedef __bf16 bf16x4 __attribute__((ext_vector_type(4)));
typedef __bf16 bf16x8 __attribute__((ext_vector_type(8)));
typedef float f32x4 __attribute__((ext_vector_type(4)));

#define LDS_CAST(p) ((__attribute__((address_space(3))) void*)(p))
#define GLB_CAST(p) ((const __attribute__((address_space(1))) void*)(p))

__device__ __forceinline__ void gl_lds16(const void* g, void* l) {
  __builtin_amdgcn_global_load_lds(GLB_CAST(g), LDS_CAST(l), 16, 0, 0);
}

#define MFMA16(a,b,c) __builtin_amdgcn_mfma_f32_16x16x32_bf16((a),(b),(c),0,0,0)
#define BARRIER() __builtin_amdgcn_s_barrier()
#define PRIO(n)  __builtin_amdgcn_s_setprio(n)

template<int N> __device__ __forceinline__ void vmw() {
  if constexpr (N == 8)      asm volatile("s_waitcnt vmcnt(8)" ::: "memory");
  else if constexpr (N == 4) asm volatile("s_waitcnt vmcnt(4)" ::: "memory");
  else if constexpr (N == 0) asm volatile("s_waitcnt vmcnt(0)" ::: "memory");
  // N == -1: no wait
}

static constexpr int M_TOT = 4096, H_DIM = 4096, I_DIM = 14336;

// ---------------------------------------------------------------------------
// fp32 -> bf16 conversion (float4 in, bf16x4 out), grid-stride
// ---------------------------------------------------------------------------
__global__ __launch_bounds__(256)
void k_conv(const float4* __restrict__ src, bf16x4* __restrict__ dst, long n4)
{
  long stride = (long)gridDim.x * blockDim.x;
  for (long i = (long)blockIdx.x * blockDim.x + threadIdx.x; i < n4; i += stride) {
    float4 v = src[i];
    bf16x4 o;
    o[0] = (bf16_t)v.x; o[1] = (bf16_t)v.y; o[2] = (bf16_t)v.z; o[3] = (bf16_t)v.w;
    dst[i] = o;
  }
}

// ===========================================================================
// GEMM1: A[M,I] = silu(X Wg^T) * (X Wu^T). BM=256, BN=128, BK=32.
// R5 structure + REGISTER FRAGMENT PREFETCH (distance-1 pipeline):
//   body T: vmcnt(4) -> barrier -> ds_read frags(T+1) into alternate set ->
//           stage(T+3) -> MFMA on frags(T).
// Two named fragment sets (A/B), loop unrolled x2 for static indexing.
// 4 LDS bufs x 32 KiB (X 16K | G 8K | U 8K), lead-3 staging, 0-conflict
// swizzle (colb ^= rowbit3<<5, src pre-XOR'd).
// ===========================================================================
__global__ __launch_bounds__(512, 2)
void k_gateup9(const bf16_t* __restrict__ X, const bf16_t* __restrict__ Wg,
               const bf16_t* __restrict__ Wu, bf16_t* __restrict__ Aout)
{
  __shared__ __align__(1024) char lds[131072];
  const int tid = threadIdx.x, wave = tid >> 6, lane = tid & 63;
  const int lr = lane & 15, kg = lane >> 4;
  const int xm = ((lr >> 3) & 1) << 5;
  const int wm = wave >> 2, wn = wave & 3;
  const int wb = wave * 1024;

  // tn-major XCD mapping (halves FETCH vs naive)
  const int bid = blockIdx.x;                 // grid = 1792
  const int bq  = bid >> 3;                   // 0..223
  const int tn  = (bid & 7) * 14 + (bq >> 4); // 0..111
  const int tm  = bq & 15;                    // 0..15

  const int srow  = tid >> 2;                                   // 0..127
  const int scolb = ((tid & 3) * 16) ^ (((tid >> 5) & 1) << 5); // pre-swizzled

  const bf16_t* gX = X  + (size_t)(tm * 256 + srow) * H_DIM + (scolb >> 1);
  const bf16_t* gG = Wg + (size_t)(tn * 128 + srow) * H_DIM + (scolb >> 1);
  const bf16_t* gU = Wu + (size_t)(tn * 128 + srow) * H_DIM + (scolb >> 1);
  const size_t xh = (size_t)128 * H_DIM;

  const int ck   = (kg * 16) ^ xm;
  const int offA = (wm * 128 + lr) * 64 + ck;            // + f*1024, f=0..7
  const int offG = 16384 + (wn * 32 + lr) * 64 + ck;     // + n*1024, n=0..1
  const int offU = offG + 8192;

  const f32x4 vz = {0.f, 0.f, 0.f, 0.f};
  f32x4 accg[8][2], accu[8][2];
#pragma unroll
  for (int m = 0; m < 8; ++m)
#pragma unroll
    for (int n = 0; n < 2; ++n) { accg[m][n] = vz; accu[m][n] = vz; }

#define G1_STAGE(TT)                                                         \
  { char* sb = lds + (((TT) & 3) << 15) + wb;                                \
    const int kc = (TT) * 32;                                                \
    gl_lds16(gX + kc,      sb);                                              \
    gl_lds16(gX + xh + kc, sb + 8192);                                       \
    gl_lds16(gG + kc,      sb + 16384);                                      \
    gl_lds16(gU + kc,      sb + 24576); }

#define G1_READS(SET, TT)                                                    \
  { const char* rb = lds + (((TT) & 3) << 15);                               \
    _Pragma("unroll") for (int f = 0; f < 8; ++f)                            \
      a##SET[f] = *(const bf16x8*)(rb + offA + f * 1024);                    \
    _Pragma("unroll") for (int n = 0; n < 2; ++n) {                          \
      bg##SET[n] = *(const bf16x8*)(rb + offG + n * 1024);                   \
      bu##SET[n] = *(const bf16x8*)(rb + offU + n * 1024); } }

#define G1_MFMA(SET)                                                         \
  { PRIO(1);                                                                 \
    _Pragma("unroll") for (int m = 0; m < 8; ++m)                            \
    _Pragma("unroll") for (int n = 0; n < 2; ++n) {                          \
      accg[m][n] = MFMA16(a##SET[m], bg##SET[n], accg[m][n]);                \
      accu[m][n] = MFMA16(a##SET[m], bu##SET[n], accu[m][n]); }              \
    PRIO(0); }

  bf16x8 aA[8], bgA[2], buA[2];
  bf16x8 aB[8], bgB[2], buB[2];

  // prologue: stage tiles 0..2, force tile0, read frags(0) into set A
  G1_STAGE(0); G1_STAGE(1); G1_STAGE(2);
  vmw<8>(); BARRIER();
  G1_READS(A, 0);

  const int NT = H_DIM / 32;                  // 128
  for (int T = 0; T < NT - 4; T += 2) {
    vmw<4>(); BARRIER();                      // tile T+1 staged (all waves)
    G1_READS(B, T + 1);                       // LDS reads overlap MFMA below
    G1_STAGE(T + 3);
    G1_MFMA(A);                               // frags(T)
    vmw<4>(); BARRIER();                      // tile T+2 staged
    G1_READS(A, T + 2);
    G1_STAGE(T + 4);
    G1_MFMA(B);                               // frags(T+1)
  }
  // peeled tail: T = NT-4 .. NT-1  (124..127)
  vmw<4>(); BARRIER(); G1_READS(B, NT - 3); G1_STAGE(NT - 1); G1_MFMA(A);
  vmw<4>(); BARRIER(); G1_READS(A, NT - 2);                   G1_MFMA(B);
  vmw<0>(); BARRIER(); G1_READS(B, NT - 1);                   G1_MFMA(A);
  G1_MFMA(B);
#undef G1_STAGE
#undef G1_READS
#undef G1_MFMA

  // epilogue: C/D col = lane&15, row = (lane>>4)*4 + e
  const int r0 = tm * 256 + wm * 128 + kg * 4;
  const int c0 = tn * 128 + wn * 32 + lr;
#pragma unroll
  for (int m = 0; m < 8; ++m)
#pragma unroll
    for (int n = 0; n < 2; ++n)
#pragma unroll
      for (int e = 0; e < 4; ++e) {
        float g = accg[m][n][e];
        float u = accu[m][n][e];
        float s = g / (1.0f + __expf(-g));
        Aout[(size_t)(r0 + m * 16 + e) * I_DIM + c0 + n * 16] = (bf16_t)(s * u);
      }
}

// ===========================================================================
// GEMM2: D[M,H] = A Wd^T. BM=BN=256, BK=32, K=I_DIM. Per-wave 128x64.
// Same distance-1 register prefetch pipeline.
// 4 bufs x 32 KiB (A 16K | B 16K).
// ===========================================================================
__global__ __launch_bounds__(512, 2)
void k_down9(const bf16_t* __restrict__ Aa, const bf16_t* __restrict__ Wd,
             float* __restrict__ D)
{
  __shared__ __align__(1024) char lds[131072];
  const int tid = threadIdx.x, wave = tid >> 6, lane = tid & 63;
  const int lr = lane & 15, kg = lane >> 4;
  const int xm = ((lr >> 3) & 1) << 5;
  const int wm = wave >> 2, wn = wave & 3;
  const int wb = wave * 1024;

  const int bid = blockIdx.x;                 // grid = 256
  const int bq  = bid >> 3;                   // 0..31
  const int tn  = (bid & 7) * 2 + (bq >> 4);  // 0..15
  const int tm  = bq & 15;                    // 0..15

  const int srow  = tid >> 2;
  const int scolb = ((tid & 3) * 16) ^ (((tid >> 5) & 1) << 5);

  const bf16_t* gA = Aa + (size_t)(tm * 256 + srow) * I_DIM + (scolb >> 1);
  const bf16_t* gB = Wd + (size_t)(tn * 256 + srow) * I_DIM + (scolb >> 1);
  const size_t hI = (size_t)128 * I_DIM;

  const int ck   = (kg * 16) ^ xm;
  const int offA = (wm * 128 + lr) * 64 + ck;            // + f*1024
  const int offB = 16384 + (wn * 64 + lr) * 64 + ck;     // + n*1024, n=0..3

  const f32x4 vz = {0.f, 0.f, 0.f, 0.f};
  f32x4 acc[8][4];
#pragma unroll
  for (int m = 0; m < 8; ++m)
#pragma unroll
    for (int n = 0; n < 4; ++n) acc[m][n] = vz;

#define G2_STAGE(TT)                                                         \
  { char* sb = lds + (((TT) & 3) << 15) + wb;                                \
    const int kc = (TT) * 32;                                                \
    gl_lds16(gA + kc,      sb);                                              \
    gl_lds16(gA + hI + kc, sb + 8192);                                       \
    gl_lds16(gB + kc,      sb + 16384);                                      \
    gl_lds16(gB + hI + kc, sb + 24576); }

#define G2_READS(SET, TT)                                                    \
  { const char* rb = lds + (((TT) & 3) << 15);                               \
    _Pragma("unroll") for (int f = 0; f < 8; ++f)                            \
      a##SET[f] = *(const bf16x8*)(rb + offA + f * 1024);                    \
    _Pragma("unroll") for (int n = 0; n < 4; ++n)                            \
      b##SET[n] = *(const bf16x8*)(rb + offB + n * 1024); }

#define G2_MFMA(SET)                                                         \
  { PRIO(1);                                                                 \
    _Pragma("unroll") for (int m = 0; m < 8; ++m)                            \
    _Pragma("unroll") for (int n = 0; n < 4; ++n)                            \
      acc[m][n] = MFMA16(a##SET[m], b##SET[n], acc[m][n]);                   \
    PRIO(0); }

  bf16x8 aA[8], bA[4];
  bf16x8 aB[8], bB[4];

  G2_STAGE(0); G2_STAGE(1); G2_STAGE(2);
  vmw<8>(); BARRIER();
  G2_READS(A, 0);

  const int NT = I_DIM / 32;                  // 448
  for (int T = 0; T < NT - 4; T += 2) {
    vmw<4>(); BARRIER();
    G2_READS(B, T + 1);
    G2_STAGE(T + 3);
    G2_MFMA(A);
    vmw<4>(); BARRIER();
    G2_READS(A, T + 2);
    G2_STAGE(T + 4);
    G2_MFMA(B);
  }
  vmw<4>(); BARRIER(); G2_READS(B, NT - 3); G2_STAGE(NT - 1); G2_MFMA(A);
  vmw<4>(); BARRIER(); G2_READS(A, NT - 2);                   G2_MFMA(B);
  vmw<0>(); BARRIER(); G2_READS(B, NT - 1);                   G2_MFMA(A);
  G2_MFMA(B);
#undef G2_STAGE
#undef G2_READS
#undef G2_MFMA

  const int r0 = tm * 256 + wm * 128 + kg * 4;
  const int c0 = tn * 256 + wn * 64 + lr;
#pragma unroll
  for (int m = 0; m < 8; ++m)
#pragma unroll
    for (int n = 0; n < 4; ++n)
#pragma unroll
      for (int e = 0; e < 4; ++e)
        D[(size_t)(r0 + m * 16 + e) * H_DIM + c0 + n * 16] = acc[m][n][e];
}

// ---------------------------------------------------------------------------
extern "C" void kernel_launch(void* const* d_in, const int* in_sizes, int n_in,
                              void* d_out, int out_size, void* d_ws, size_t ws_size,
                              hipStream_t stream) {
  const float* x  = (const float*)d_in[0];
  const float* wg = (const float*)d_in[1];
  const float* wu = (const float*)d_in[2];
  const float* wd = (const float*)d_in[3];
  float* out = (float*)d_out;

  const size_t A_BYTES = (size_t)M_TOT * I_DIM * 2;
  const size_t X_BYTES = (size_t)M_TOT * H_DIM * 2;
  const size_t W_BYTES = (size_t)I_DIM * H_DIM * 2;
  char* ws = (char*)d_ws;
  bf16_t* Ab  = (bf16_t*)(ws);
  bf16_t* Xb  = (bf16_t*)(ws + A_BYTES);
  bf16_t* Wgb = (bf16_t*)(ws + A_BYTES + X_BYTES);
  bf16_t* Wub = (bf16_t*)(ws + A_BYTES + X_BYTES + W_BYTES);
  bf16_t* Wdb = Wgb;   // reuse after k_gateup9 consumed Wgb

  const long nX = (long)M_TOT * H_DIM / 4;
  const long nW = (long)I_DIM * H_DIM / 4;

  k_conv<<<dim3(2048), dim3(256), 0, stream>>>((const float4*)x,  (bf16x4*)Xb,  nX);
  k_conv<<<dim3(2048), dim3(256), 0, stream>>>((const float4*)wg, (bf16x4*)Wgb, nW);
  k_conv<<<dim3(2048), dim3(256), 0, stream>>>((const float4*)wu, (bf16x4*)Wub, nW);

  k_gateup9<<<dim3(16 * 112), dim3(512), 0, stream>>>(Xb, Wgb, Wub, Ab);

  k_conv<<<dim3(2048), dim3(256), 0, stream>>>((const float4*)wd, (bf16x4*)Wdb, nW);

  k_down9<<<dim3(16 * 16), dim3(512), 0, stream>>>(Ab, Wdb, out);
}